// Round 9
// baseline (837.962 us; speedup 1.0000x reference)
//
#include <hip/hip_runtime.h>

// B=4, N=M=4096, D=128.
// d_out (floats): match_mask [4*4096*4096] | pairs [16384] (as float) | top_dists [16384]
// ws fast path:
//   bytes [0, 131072):        x2 [16384] f32 | y2 [16384] f32
//   bytes [131072, 25296896): planes, 6 x PS elems bf16 (x:h,m,l then y:h,m,l)
//     chunk layout: [b(4)][kh(2)][tile(32)] -> 8192-elem (16 KiB) chunk
//     within chunk: [rb(8)][kc(2)][lane(64)][e(8)], value = in[b][tile*128+rb*16+(l&15)][kh*64+kc*32+(l>>4)*8+e]
//   then pv [16384*2] f32 | pi [16384*2] i32
// Products: hh, hm, mh, mm, hl, lh. Per kh: B=h -> A{h,m,l}; B=m -> A{h,m}; B=l -> A{h}.
// Round-9: 9-wave blocks. Waves 0-7: 3-phase pair-staged GEMM pipeline (loads-only
// vmcnt FIFO -> clean counted waits). Wave 8: dedicated zero-store streamer (its
// stores live in its own per-wave vmcnt FIFO and never poison compute waits).

typedef float  f32x4  __attribute__((ext_vector_type(4)));
typedef short  bf16x8 __attribute__((ext_vector_type(8)));

#define PS ((size_t)2097152)

#define WAITVM_(N) asm volatile("s_waitcnt vmcnt(" #N ")" ::: "memory")
#define WAITVM(N)  WAITVM_(N)
#define BAR        __builtin_amdgcn_s_barrier()

__device__ __forceinline__ unsigned short f2bf(float x) {
    unsigned u = __float_as_uint(x);
    u += 0x7FFFu + ((u >> 16) & 1u);
    return (unsigned short)(u >> 16);
}
__device__ __forceinline__ float bf2f(unsigned short s) {
    return __uint_as_float(((unsigned)s) << 16);
}
__device__ __forceinline__ void gload_lds16(const void* g, void* l) {
    __builtin_amdgcn_global_load_lds(
        (const __attribute__((address_space(1))) void*)g,
        (__attribute__((address_space(3))) void*)l, 16, 0, 0);
}

// ---- split f32 -> 3 bf16 planes (fragment order) + fused row sum-of-squares ----
__global__ __launch_bounds__(256) void k_prep(const float* __restrict__ xd,
                                              const float* __restrict__ yd,
                                              unsigned short* __restrict__ pl,
                                              float* __restrict__ ws) {
    __shared__ float sm[4][16];
    int bid  = blockIdx.x;            // 0..2047
    int i    = bid >> 10;
    int b    = (bid >> 8) & 3;
    int rblk = bid & 255;
    int tid  = threadIdx.x;
    int kb   = tid >> 6;
    int l    = tid & 63;
    int r    = rblk * 16 + (l & 15);
    int k0   = kb * 32 + ((l >> 4) & 3) * 8;
    const float* src = (i ? yd : xd) + ((size_t)(b * 4096 + r) * 128 + k0);
    float v[8];
    *reinterpret_cast<float4*>(v)     = *reinterpret_cast<const float4*>(src);
    *reinterpret_cast<float4*>(v + 4) = *reinterpret_cast<const float4*>(src + 4);
    bf16x8 hv, mv, lv;
    float s = 0.f;
    #pragma unroll
    for (int e = 0; e < 8; ++e) {
        float x = v[e];
        s = fmaf(x, x, s);
        unsigned short h  = f2bf(x);
        float r1 = x - bf2f(h);
        unsigned short m  = f2bf(r1);
        float r2 = r1 - bf2f(m);
        unsigned short lo = f2bf(r2);
        hv[e] = (short)h; mv[e] = (short)m; lv[e] = (short)lo;
    }
    int rt = rblk >> 3, rb = rblk & 7, kh = kb >> 1, kc = kb & 1;
    size_t base = ((((size_t)((b * 2 + kh) * 32 + rt)) * 8 + rb) * 2 + kc) * 512 + (size_t)l * 8;
    unsigned short* dst = pl + (size_t)(i * 3) * PS;
    *reinterpret_cast<bf16x8*>(dst + base)          = hv;
    *reinterpret_cast<bf16x8*>(dst + base + PS)     = mv;
    *reinterpret_cast<bf16x8*>(dst + base + 2 * PS) = lv;
    s += __shfl_xor(s, 16);
    s += __shfl_xor(s, 32);
    if (l < 16) sm[kb][l] = s;
    __syncthreads();
    if (tid < 16) {
        float t = sm[0][tid] + sm[1][tid] + sm[2][tid] + sm[3][tid];
        ws[(i ? 16384 : 0) + b * 4096 + rblk * 16 + tid] = t;
    }
}

// ---- main: 8 compute waves (3-phase pipeline) + 1 zero-store streamer wave ----
__global__ __launch_bounds__(576, 1) void k_gemm(const float* __restrict__ mask,
                                                 const float* __restrict__ ws,
                                                 const unsigned short* __restrict__ pl,
                                                 float* __restrict__ out,
                                                 float* __restrict__ pv,
                                                 int* __restrict__ pi) {
    __shared__ __align__(16) unsigned short Ab[2][2][8192];  // 64 KiB: A planes h,m per kh
    __shared__ __align__(16) unsigned short Bp[2][2][8192];  // 64 KiB: 2 pair-slots x 2 chunks

    const int bid = blockIdx.x;        // 256 blocks = 1/CU
    const int xcd = bid & 7;
    const int b   = xcd >> 1;          // batch pinned per XCD pair
    const int ch  = xcd & 1;           // col half (2048 cols)
    const int rt  = bid >> 3;          // 128-row tile 0..31
    const int tid = threadIdx.x;
    const int w   = tid >> 6, l = tid & 63;   // w: 0..8
    const int wr  = (w >> 2) & 1, wc = w & 3; // compute waves: 2x4, 64 rows x 32 cols
    const int lg4 = (l >> 4) & 3, l15 = l & 15;
    const int g0  = b * 4096 + rt * 128;

    float x2r[16];
    #pragma unroll
    for (int mi = 0; mi < 4; ++mi)
        #pragma unroll
        for (int rg = 0; rg < 4; ++rg)
            x2r[mi * 4 + rg] = ws[g0 + wr * 64 + mi * 16 + lg4 * 4 + rg];

    bf16x8 Al[2][4][2];
    f32x4 acc[4][2];
    float pm[32], yv[2];

#define STAGE_CHUNK(NTT, C, SLOT, CH) do {                                        \
    const int kh_ = (C) / 3, bp_ = (C) % 3;                                       \
    const unsigned short* Bc_ = pl + (size_t)(3 + bp_) * PS                       \
        + (((size_t)((b * 2 + kh_) * 32 + ch * 16 + (NTT))) << 13);               \
    const char* g_ = (const char*)Bc_ + w * 1024 + l * 16;                        \
    char* d_ = (char*)(&Bp[SLOT][CH][0]) + w * 1024;                              \
    gload_lds16(g_, d_);                                                          \
    gload_lds16(g_ + 8192, d_ + 8192);                                            \
} while (0)

#define MLOADALL(NT) do {                                                         \
    _Pragma("unroll") for (int K = 0; K < 32; ++K) {                              \
        const int mi_ = K >> 3, rg_ = (K >> 1) & 3, ni_ = K & 1;                  \
        pm[K] = mask[(size_t)(g0 + wr * 64 + mi_ * 16 + lg4 * 4 + rg_) * 4096     \
                     + (ch * 2048 + (NT) * 128 + wc * 32 + ni_ * 16 + l15)];      \
    }                                                                             \
    yv[0] = ws[16384 + b * 4096 + ch * 2048 + (NT) * 128 + wc * 32 + l15];        \
    yv[1] = ws[16384 + b * 4096 + ch * 2048 + (NT) * 128 + wc * 32 + 16 + l15];   \
} while (0)

// streamer: zero-store quota (1 KiB per instr; 64 instrs per nt across 3 phases)
#define ZQ(BASE, CNT) do {                                                        \
    _Pragma("unroll") for (int k = 0; k < (CNT); ++k) {                           \
        const int i_ = nt * 64 + (BASE) + k;                                      \
        const int row_ = i_ >> 3, cb_ = i_ & 7;                                   \
        const f32x4 z_ = (f32x4){0.f, 0.f, 0.f, 0.f};                             \
        *reinterpret_cast<f32x4*>(out + (size_t)(g0 + row_) * 4096                \
            + ch * 2048 + cb_ * 256 + l * 4) = z_;                                \
    }                                                                             \
} while (0)

// BP: 0=h (A h,m LDS + A-l regs), 1=m (A h,m), 2=l (A h only)
#define COMPUTE(BP, KH, SLOT, CH) do {                                            \
    bf16x8 bfr_[2][2];                                                            \
    _Pragma("unroll") for (int ni = 0; ni < 2; ++ni)                              \
    _Pragma("unroll") for (int kc = 0; kc < 2; ++kc)                              \
        bfr_[ni][kc] = *reinterpret_cast<const bf16x8*>(                          \
            &Bp[SLOT][CH][(((wc * 2 + ni) * 2 + kc) << 9) + l * 8]);              \
    __builtin_amdgcn_s_setprio(1);                                                \
    _Pragma("unroll") for (int mi = 0; mi < 4; ++mi)                              \
    _Pragma("unroll") for (int kc = 0; kc < 2; ++kc) {                            \
        bf16x8 af_ = *reinterpret_cast<const bf16x8*>(                            \
            &Ab[KH][0][(((wr * 4 + mi) * 2 + kc) << 9) + l * 8]);                 \
        _Pragma("unroll") for (int ni = 0; ni < 2; ++ni)                          \
            acc[mi][ni] = __builtin_amdgcn_mfma_f32_16x16x32_bf16(                \
                af_, bfr_[ni][kc], acc[mi][ni], 0, 0, 0);                         \
    }                                                                             \
    if ((BP) <= 1) {                                                              \
        _Pragma("unroll") for (int mi = 0; mi < 4; ++mi)                          \
        _Pragma("unroll") for (int kc = 0; kc < 2; ++kc) {                        \
            bf16x8 af_ = *reinterpret_cast<const bf16x8*>(                        \
                &Ab[KH][1][(((wr * 4 + mi) * 2 + kc) << 9) + l * 8]);             \
            _Pragma("unroll") for (int ni = 0; ni < 2; ++ni)                      \
                acc[mi][ni] = __builtin_amdgcn_mfma_f32_16x16x32_bf16(            \
                    af_, bfr_[ni][kc], acc[mi][ni], 0, 0, 0);                     \
        }                                                                         \
    }                                                                             \
    if ((BP) == 0) {                                                              \
        _Pragma("unroll") for (int mi = 0; mi < 4; ++mi)                          \
        _Pragma("unroll") for (int kc = 0; kc < 2; ++kc)                          \
        _Pragma("unroll") for (int ni = 0; ni < 2; ++ni)                          \
            acc[mi][ni] = __builtin_amdgcn_mfma_f32_16x16x32_bf16(                \
                Al[KH][mi][kc], bfr_[ni][kc], acc[mi][ni], 0, 0, 0);              \
    }                                                                             \
    __builtin_amdgcn_s_setprio(0);                                                \
} while (0)

    // ---- prologue (compute waves): A h,m -> LDS; A-l -> regs; B c0,c1 -> slot0;
    //      masks for nt0; then drain loads and publish ----
    if (w < 8) {
        #pragma unroll
        for (int c = 0; c < 4; ++c) {
            const int kh = c >> 1, ap = c & 1;
            const unsigned short* Ac = pl + (size_t)ap * PS
                + (((size_t)((b * 2 + kh) * 32 + rt)) << 13);
            const char* g = (const char*)Ac + w * 1024 + l * 16;
            char* dd = (char*)(&Ab[kh][ap][0]) + w * 1024;
            gload_lds16(g, dd);
            gload_lds16(g + 8192, dd + 8192);
        }
        #pragma unroll
        for (int kh = 0; kh < 2; ++kh) {
            const unsigned short* Ac = pl + (size_t)2 * PS
                + (((size_t)((b * 2 + kh) * 32 + rt)) << 13);
            #pragma unroll
            for (int mi = 0; mi < 4; ++mi)
                #pragma unroll
                for (int kc = 0; kc < 2; ++kc)
                    Al[kh][mi][kc] = *reinterpret_cast<const bf16x8*>(
                        Ac + (((wr * 4 + mi) * 2 + kc) << 9) + l * 8);
        }
        STAGE_CHUNK(0, 0, 0, 0);
        STAGE_CHUNK(0, 1, 0, 1);
        MLOADALL(0);
        WAITVM(0);
    }
    BAR;

    const double INITD = __hiloint2double(0x7f7fffff, 0);
    double bv[16];
    #pragma unroll
    for (int q = 0; q < 16; ++q) bv[q] = INITD;

    #pragma unroll 1
    for (int nt = 0; nt < 16; ++nt) {
        const int ntn = (nt < 15) ? nt + 1 : 15;
        const int s0 = nt & 1, s1 = (nt + 1) & 1;

        // ---- P0: compute c0,c1 (slot s0); stage c2,c3 -> s1 ----
        if (w < 8) {
            #pragma unroll
            for (int mi = 0; mi < 4; ++mi)
                #pragma unroll
                for (int ni = 0; ni < 2; ++ni) acc[mi][ni] = (f32x4){0.f, 0.f, 0.f, 0.f};
            STAGE_CHUNK(nt, 2, s1, 0); STAGE_CHUNK(nt, 3, s1, 1);
            COMPUTE(0, 0, s0, 0);          // c0 = (h, kh0): 48 MFMA
            COMPUTE(1, 0, s0, 1);          // c1 = (m, kh0): 32 MFMA
            WAITVM(0);                     // retire stage (drains this nt's masks too)
        } else {
            ZQ(0, 22);
        }
        BAR;

        // ---- P1: compute c2,c3 (slot s1); stage c4,c5 -> s0 ----
        if (w < 8) {
            STAGE_CHUNK(nt, 4, s0, 0); STAGE_CHUNK(nt, 5, s0, 1);
            COMPUTE(2, 0, s1, 0);          // c2 = (l, kh0): 16 MFMA
            COMPUTE(0, 1, s1, 1);          // c3 = (h, kh1): 48 MFMA
            WAITVM(0);
        } else {
            ZQ(22, 21);
        }
        BAR;

        // ---- P2: compute c4,c5 (slot s0); stage next c0,c1 -> s1; epilogue ----
        if (w < 8) {
            STAGE_CHUNK(ntn, 0, s1, 0); STAGE_CHUNK(ntn, 1, s1, 1);
            COMPUTE(1, 1, s0, 0);          // c4 = (m, kh1): 32 MFMA
            COMPUTE(2, 1, s0, 1);          // c5 = (l, kh1): 16 MFMA
            // epilogue: packed (dist,col) f64 argmin; pm/yv retired at P0's drain
            #pragma unroll
            for (int ni = 0; ni < 2; ++ni) {
                const int c = ch * 2048 + nt * 128 + wc * 32 + ni * 16 + l15;
                #pragma unroll
                for (int mi = 0; mi < 4; ++mi) {
                    #pragma unroll
                    for (int rg = 0; rg < 4; ++rg) {
                        float d2 = fmaf(acc[mi][ni][rg], -2.0f, x2r[mi * 4 + rg]) + yv[ni];
                        float d  = sqrtf(fmaxf(d2, 0.0f)) * pm[mi * 8 + rg * 2 + ni];
                        double pk = __hiloint2double(__float_as_int(d), c);
                        bv[mi * 4 + rg] = fmin(bv[mi * 4 + rg], pk);
                    }
                }
            }
            if (nt < 15) {                 // issue next nt's masks (always consumed)
                MLOADALL(nt + 1);
                WAITVM(34);                // retire stage; 34 mask/y2 loads stay in flight
            } else {
                WAITVM(0);
            }
        } else {
            ZQ(43, 21);
        }
        BAR;
    }
#undef STAGE_CHUNK
#undef MLOADALL
#undef ZQ
#undef COMPUTE

    // ---- reduce across 16 col-lanes (packed min), then 4 col-waves via LDS ----
    #pragma unroll
    for (int off = 1; off < 16; off <<= 1) {
        #pragma unroll
        for (int q = 0; q < 16; ++q)
            bv[q] = fmin(bv[q], __shfl_xor(bv[q], off));
    }
    __syncthreads();                    // B LDS free; overlay candidates
    double* cd = reinterpret_cast<double*>(&Bp[0][0][0]);   // [128][4]
    if (w < 8 && l15 == 0) {
        #pragma unroll
        for (int mi = 0; mi < 4; ++mi)
            #pragma unroll
            for (int rg = 0; rg < 4; ++rg) {
                int rowl = wr * 64 + mi * 16 + lg4 * 4 + rg;
                cd[rowl * 4 + wc] = bv[mi * 4 + rg];
            }
    }
    __syncthreads();
    if (tid < 128) {
        double v = fmin(fmin(cd[tid * 4], cd[tid * 4 + 1]),
                        fmin(cd[tid * 4 + 2], cd[tid * 4 + 3]));
        int grow = g0 + tid;
        pv[grow * 2 + ch] = __int_as_float(__double2hiint(v));
        pi[grow * 2 + ch] = __double2loint(v);
    }
}

__global__ __launch_bounds__(256) void k_fin(const float* __restrict__ pv,
                                             const int* __restrict__ pi,
                                             float* __restrict__ out) {
    int t = blockIdx.x * 256 + threadIdx.x;   // row 0..16383
    float v0 = pv[t * 2], v1 = pv[t * 2 + 1];
    int   i0 = pi[t * 2], i1 = pi[t * 2 + 1];
    bool take1 = (v1 < v0) || (v1 == v0 && i1 < i0);
    float v  = take1 ? v1 : v0;
    int   ix = take1 ? i1 : i0;
    out[67108864 + t]         = (float)ix;            // pairs
    out[67108864 + 16384 + t] = v;                    // top_dists
    out[(size_t)t * 4096 + (size_t)ix] = 1.0f;        // one-hot
}

// ================= fallback path (needs only 384 KB ws) =================
__global__ __launch_bounds__(256) void k_rowsq(const float* __restrict__ xd,
                                               const float* __restrict__ yd,
                                               float* __restrict__ ws) {
    int tid  = threadIdx.x;
    int wid  = tid >> 6, lane = tid & 63;
    int gr   = blockIdx.x * 4 + wid;
    const float* src = (gr < 16384) ? (xd + (size_t)gr * 128)
                                    : (yd + (size_t)(gr - 16384) * 128);
    float2 v = reinterpret_cast<const float2*>(src)[lane];
    float s  = v.x * v.x + v.y * v.y;
    for (int off = 32; off > 0; off >>= 1) s += __shfl_down(s, off);
    if (lane == 0) ws[gr] = s;
}

__global__ __launch_bounds__(256, 1) void k_main_fb(const float* __restrict__ xd,
                                                    const float* __restrict__ yd,
                                                    const float* __restrict__ mask,
                                                    const float* __restrict__ ws,
                                                    float* __restrict__ pvals,
                                                    int* __restrict__ pidx,
                                                    float* __restrict__ mm) {
    __shared__ __align__(16) float Xs[128 * 128];
    __shared__ __align__(16) float Ys[128 * 128];
    const int bid  = blockIdx.x;
    const int mh   = bid & 1;
    const int rb   = (bid >> 1) & 31;
    const int b    = bid >> 6;
    const int tid  = threadIdx.x;
    const int ty   = tid >> 4;
    const int tx   = tid & 15;
    const int row0 = rb * 128;
    const int m0   = mh * 2048;
    {
        const float4 z = make_float4(0.f, 0.f, 0.f, 0.f);
        size_t base = ((size_t)(b * 4096 + row0)) * 4096 + (size_t)m0;
        for (int r = 0; r < 128; ++r) {
            float4* p = reinterpret_cast<float4*>(mm + base + (size_t)r * 4096);
            p[tid] = z; p[tid + 256] = z;
        }
    }
    {
        int lrow = tid >> 5, slot = tid & 31;
        for (int p = 0; p < 16; ++p) {
            int row  = p * 8 + lrow;
            float4 v = reinterpret_cast<const float4*>(
                           xd + ((size_t)(b * 4096 + row0 + row)) * 128)[slot];
            int ss = slot ^ (row & 31);
            *reinterpret_cast<float4*>(&Xs[row * 128 + (ss << 2)]) = v;
        }
    }
    float x2r[8];
    #pragma unroll
    for (int i = 0; i < 8; ++i) x2r[i] = ws[b * 4096 + row0 + ty * 8 + i];
    const float* y2g = ws + 16384 + b * 4096;
    float bv[8]; int bi[8];
    #pragma unroll
    for (int i = 0; i < 8; ++i) { bv[i] = 3.4e38f; bi[i] = 0; }
    __syncthreads();
    for (int tile = 0; tile < 16; ++tile) {
        const int mbase = m0 + tile * 128;
        {
            int lrow = tid >> 5, slot = tid & 31;
            for (int p = 0; p < 16; ++p) {
                int row  = p * 8 + lrow;
                float4 v = reinterpret_cast<const float4*>(
                               yd + ((size_t)(b * 4096 + mbase + row)) * 128)[slot];
                int ss = slot ^ (row & 31);
                *reinterpret_cast<float4*>(&Ys[row * 128 + (ss << 2)]) = v;
            }
        }
        __syncthreads();
        float acc[8][8];
        #pragma unroll
        for (int i = 0; i < 8; ++i)
            #pragma unroll
            for (int jj = 0; jj < 8; ++jj) acc[i][jj] = 0.0f;
        #pragma unroll 4
        for (int ks = 0; ks < 32; ++ks) {
            float4 bf[8];
            #pragma unroll
            for (int jj = 0; jj < 8; ++jj) {
                int c = jj * 16 + tx;
                bf[jj] = *reinterpret_cast<const float4*>(&Ys[c * 128 + ((ks ^ (c & 31)) << 2)]);
            }
            #pragma unroll
            for (int i = 0; i < 8; ++i) {
                int r = ty * 8 + i;
                float4 a = *reinterpret_cast<const float4*>(&Xs[r * 128 + ((ks ^ (r & 31)) << 2)]);
                #pragma unroll
                for (int jj = 0; jj < 8; ++jj) {
                    acc[i][jj] = fmaf(a.x, bf[jj].x, acc[i][jj]);
                    acc[i][jj] = fmaf(a.y, bf[jj].y, acc[i][jj]);
                    acc[i][jj] = fmaf(a.z, bf[jj].z, acc[i][jj]);
                    acc[i][jj] = fmaf(a.w, bf[jj].w, acc[i][jj]);
                }
            }
        }
        float y2v[8];
        #pragma unroll
        for (int jj = 0; jj < 8; ++jj) y2v[jj] = y2g[mbase + jj * 16 + tx];
        #pragma unroll
        for (int i = 0; i < 8; ++i) {
            int r = ty * 8 + i;
            const float* mr = mask + ((size_t)(b * 4096 + row0 + r)) * 4096;
            #pragma unroll
            for (int jj = 0; jj < 8; ++jj) {
                int   m  = mbase + jj * 16 + tx;
                float d2 = x2r[i] + y2v[jj] - 2.0f * acc[i][jj];
                float d  = sqrtf(fmaxf(d2, 0.0f)) * mr[m];
                if (d < bv[i]) { bv[i] = d; bi[i] = m; }
            }
        }
        __syncthreads();
    }
    float* candv = Xs;
    int*   candi = reinterpret_cast<int*>(Xs + 2048);
    #pragma unroll
    for (int i = 0; i < 8; ++i) {
        int r = ty * 8 + i;
        candv[r * 16 + tx] = bv[i];
        candi[r * 16 + tx] = bi[i];
    }
    __syncthreads();
    if (tid < 128) {
        int   r  = tid;
        float v  = candv[r * 16];
        int   ix = candi[r * 16];
        for (int t = 1; t < 16; ++t) {
            float v2 = candv[r * 16 + t];
            int   i2 = candi[r * 16 + t];
            if (v2 < v || (v2 == v && i2 < ix)) { v = v2; ix = i2; }
        }
        int grow = b * 4096 + row0 + r;
        pvals[grow * 2 + mh] = v;
        pidx [grow * 2 + mh] = ix;
    }
}

__global__ __launch_bounds__(256) void k_fin_fb(const float* __restrict__ pvals,
                                                const int* __restrict__ pidx,
                                                float* __restrict__ out) {
    int t = blockIdx.x * 256 + threadIdx.x;
    float v0 = pvals[t * 2], v1 = pvals[t * 2 + 1];
    int   i0 = pidx [t * 2], i1 = pidx [t * 2 + 1];
    bool take1 = (v1 < v0) || (v1 == v0 && i1 < i0);
    float v  = take1 ? v1 : v0;
    int   ix = take1 ? i1 : i0;
    out[67108864 + t]         = (float)ix;
    out[67108864 + 16384 + t] = v;
    out[(size_t)t * 4096 + (size_t)ix] = 1.0f;
}

extern "C" void kernel_launch(void* const* d_in, const int* in_sizes, int n_in,
                              void* d_out, int out_size, void* d_ws, size_t ws_size,
                              hipStream_t stream) {
    const float* xd   = (const float*)d_in[0];
    const float* yd   = (const float*)d_in[1];
    const float* mask = (const float*)d_in[2];
    float* out = (float*)d_out;
    float* wsf = (float*)d_ws;

    const size_t need = 131072 + 6 * PS * 2 + 262144;   // 25,559,040
    if (ws_size >= need) {
        unsigned short* pl = (unsigned short*)((char*)d_ws + 131072);
        float* pv = (float*)((char*)d_ws + 131072 + 6 * PS * 2);
        int*   pi = (int*)  ((char*)d_ws + 131072 + 6 * PS * 2 + 131072);
        k_prep <<<2048, 256, 0, stream>>>(xd, yd, pl, wsf);
        k_gemm <<<256,  576, 0, stream>>>(mask, wsf, pl, out, pv, pi);
        k_fin  <<<64,   256, 0, stream>>>(pv, pi, out);
    } else {
        float* pvals = wsf + 32768;
        int*   pidx  = (int*)(wsf + 65536);
        k_rowsq  <<<8192, 256, 0, stream>>>(xd, yd, wsf);
        k_main_fb<<<256,  256, 0, stream>>>(xd, yd, mask, wsf, pvals, pidx, out);
        k_fin_fb <<<64,   256, 0, stream>>>(pvals, pidx, out);
    }
}

// Round 10
// 229.739 us; speedup vs baseline: 3.6475x; 3.6475x over previous
//
#include <hip/hip_runtime.h>

// B=4, N=M=4096, D=128.
// d_out (floats): match_mask [4*4096*4096] | pairs [16384] (as float) | top_dists [16384]
// ws fast path:
//   bytes [0, 131072):        x2 [16384] f32 | y2 [16384] f32
//   bytes [131072, 25296896): planes, 6 x PS elems bf16 (x:h,m,l then y:h,m,l)
//     chunk layout: [b(4)][kh(2)][tile(32)] -> 8192-elem (16 KiB) chunk
//     within chunk: [rb(8)][kc(2)][lane(64)][e(8)], value = in[b][tile*128+rb*16+(l&15)][kh*64+kc*32+(l>>4)*8+e]
//   then pv [16384*2] f32 | pi [16384*2] i32
// Products: hh, hm, mh, mm, hl, lh. Per kh: B=h -> A{h,m,l}; B=m -> A{h,m}; B=l -> A{h}.
// Round-10: 2 phases per nt. Per phase: [MLOAD | fence | STAGE3 | fence | ZST] + 96 MFMA.
// Counted waits NA=4 / NB=4 / NE=10 derived from the pinned per-wave FIFO order;
// newest stage + stores always stay in flight (no forced store drains).

typedef float  f32x4  __attribute__((ext_vector_type(4)));
typedef short  bf16x8 __attribute__((ext_vector_type(8)));

#define PS ((size_t)2097152)

#define WAITVM_(N) asm volatile("s_waitcnt vmcnt(" #N ")" ::: "memory")
#define WAITVM(N)  WAITVM_(N)
#define BAR        __builtin_amdgcn_s_barrier()
#define FENCE      asm volatile("" ::: "memory")

__device__ __forceinline__ unsigned short f2bf(float x) {
    unsigned u = __float_as_uint(x);
    u += 0x7FFFu + ((u >> 16) & 1u);
    return (unsigned short)(u >> 16);
}
__device__ __forceinline__ float bf2f(unsigned short s) {
    return __uint_as_float(((unsigned)s) << 16);
}
__device__ __forceinline__ void gload_lds16(const void* g, void* l) {
    __builtin_amdgcn_global_load_lds(
        (const __attribute__((address_space(1))) void*)g,
        (__attribute__((address_space(3))) void*)l, 16, 0, 0);
}

// ---- split f32 -> 3 bf16 planes (fragment order) + fused row sum-of-squares ----
__global__ __launch_bounds__(256) void k_prep(const float* __restrict__ xd,
                                              const float* __restrict__ yd,
                                              unsigned short* __restrict__ pl,
                                              float* __restrict__ ws) {
    __shared__ float sm[4][16];
    int bid  = blockIdx.x;            // 0..2047
    int i    = bid >> 10;
    int b    = (bid >> 8) & 3;
    int rblk = bid & 255;
    int tid  = threadIdx.x;
    int kb   = tid >> 6;
    int l    = tid & 63;
    int r    = rblk * 16 + (l & 15);
    int k0   = kb * 32 + ((l >> 4) & 3) * 8;
    const float* src = (i ? yd : xd) + ((size_t)(b * 4096 + r) * 128 + k0);
    float v[8];
    *reinterpret_cast<float4*>(v)     = *reinterpret_cast<const float4*>(src);
    *reinterpret_cast<float4*>(v + 4) = *reinterpret_cast<const float4*>(src + 4);
    bf16x8 hv, mv, lv;
    float s = 0.f;
    #pragma unroll
    for (int e = 0; e < 8; ++e) {
        float x = v[e];
        s = fmaf(x, x, s);
        unsigned short h  = f2bf(x);
        float r1 = x - bf2f(h);
        unsigned short m  = f2bf(r1);
        float r2 = r1 - bf2f(m);
        unsigned short lo = f2bf(r2);
        hv[e] = (short)h; mv[e] = (short)m; lv[e] = (short)lo;
    }
    int rt = rblk >> 3, rb = rblk & 7, kh = kb >> 1, kc = kb & 1;
    size_t base = ((((size_t)((b * 2 + kh) * 32 + rt)) * 8 + rb) * 2 + kc) * 512 + (size_t)l * 8;
    unsigned short* dst = pl + (size_t)(i * 3) * PS;
    *reinterpret_cast<bf16x8*>(dst + base)          = hv;
    *reinterpret_cast<bf16x8*>(dst + base + PS)     = mv;
    *reinterpret_cast<bf16x8*>(dst + base + 2 * PS) = lv;
    s += __shfl_xor(s, 16);
    s += __shfl_xor(s, 32);
    if (l < 16) sm[kb][l] = s;
    __syncthreads();
    if (tid < 16) {
        float t = sm[0][tid] + sm[1][tid] + sm[2][tid] + sm[3][tid];
        ws[(i ? 16384 : 0) + b * 4096 + rblk * 16 + tid] = t;
    }
}

// ---- main: 2-phase/nt, counted-wait pipeline, A-l in regs, packed-f64 argmin ----
__global__ __launch_bounds__(512, 1) void k_gemm(const float* __restrict__ mask,
                                                 const float* __restrict__ ws,
                                                 const unsigned short* __restrict__ pl,
                                                 float* __restrict__ out,
                                                 float* __restrict__ pv,
                                                 int* __restrict__ pi) {
    __shared__ __align__(16) unsigned short Ab[2][2][8192];  // 64 KiB: A planes h,m per kh
    __shared__ __align__(16) unsigned short Bp[2][3][8192];  // 96 KiB: [kh-slot][plane h,m,l]

    const int bid = blockIdx.x;        // 256 blocks = 1/CU
    const int xcd = bid & 7;
    const int b   = xcd >> 1;          // batch pinned per XCD pair
    const int ch  = xcd & 1;           // col half (2048 cols)
    const int rt  = bid >> 3;          // 128-row tile 0..31
    const int tid = threadIdx.x;
    const int w   = tid >> 6, l = tid & 63;
    const int wr  = w >> 2, wc = w & 3;     // 2x4 waves: 64 rows x 32 cols each
    const int lg4 = (l >> 4) & 3, l15 = l & 15;
    const int g0  = b * 4096 + rt * 128;

    float x2r[16];
    #pragma unroll
    for (int mi = 0; mi < 4; ++mi)
        #pragma unroll
        for (int rg = 0; rg < 4; ++rg)
            x2r[mi * 4 + rg] = ws[g0 + wr * 64 + mi * 16 + lg4 * 4 + rg];

    // per-thread mask row base (rows wr*64 + lg4*4 + mi*16 + rg; cols ch*2048+...)
    const float* mrow = mask + (size_t)(g0 + wr * 64 + lg4 * 4) * 4096
                        + ch * 2048 + wc * 32 + l15;
    const float* y2b  = ws + 16384 + b * 4096 + ch * 2048 + wc * 32 + l15;

    // ---- prologue: A h,m -> LDS; A-l -> regs; B nt0 kh0 -> slot0; drain ----
    #pragma unroll
    for (int c = 0; c < 4; ++c) {
        const int kh = c >> 1, ap = c & 1;
        const unsigned short* Ac = pl + (size_t)ap * PS
            + (((size_t)((b * 2 + kh) * 32 + rt)) << 13);
        const char* g = (const char*)Ac + w * 1024 + l * 16;
        char* dd = (char*)(&Ab[kh][ap][0]) + w * 1024;
        gload_lds16(g, dd);
        gload_lds16(g + 8192, dd + 8192);
    }
    bf16x8 Al[2][4][2];
    #pragma unroll
    for (int kh = 0; kh < 2; ++kh) {
        const unsigned short* Ac = pl + (size_t)2 * PS
            + (((size_t)((b * 2 + kh) * 32 + rt)) << 13);
        #pragma unroll
        for (int mi = 0; mi < 4; ++mi)
            #pragma unroll
            for (int kc = 0; kc < 2; ++kc)
                Al[kh][mi][kc] = *reinterpret_cast<const bf16x8*>(
                    Ac + (((wr * 4 + mi) * 2 + kc) << 9) + l * 8);
    }

#define STAGE3(NTT, KH, SLOT) do {                                                \
    _Pragma("unroll") for (int bp_ = 0; bp_ < 3; ++bp_) {                         \
        const unsigned short* Bc_ = pl + (size_t)(3 + bp_) * PS                   \
            + (((size_t)((b * 2 + (KH)) * 32 + ch * 16 + (NTT))) << 13);          \
        const char* g_ = (const char*)Bc_ + w * 1024 + l * 16;                    \
        char* d_ = (char*)(&Bp[SLOT][bp_][0]) + w * 1024;                         \
        gload_lds16(g_, d_);                                                      \
        gload_lds16(g_ + 8192, d_ + 8192);                                        \
    }                                                                             \
} while (0)

#define MLOAD16(NT, NI) do {                                                      \
    _Pragma("unroll") for (int mi_ = 0; mi_ < 4; ++mi_)                           \
    _Pragma("unroll") for (int rg_ = 0; rg_ < 4; ++rg_)                           \
        pm[mi_ * 8 + rg_ * 2 + (NI)] =                                            \
            mrow[(size_t)(mi_ * 16 + rg_) * 4096 + (NT) * 128 + (NI) * 16];       \
} while (0)

#define ZST(NT, I) do {                                                           \
    const f32x4 z_ = (f32x4){0.f, 0.f, 0.f, 0.f};                                 \
    const int r_ = (tid >> 5) * 8 + (I);                                          \
    *reinterpret_cast<f32x4*>(out + (size_t)(g0 + r_) * 4096                      \
        + ch * 2048 + (NT) * 128 + ((tid & 31) << 2)) = z_;                       \
} while (0)

// BP: 0=h (A h,m LDS + A-l regs), 1=m (A h,m), 2=l (A h only)
#define COMPUTE_ONE(BP, KH, SLOT) do {                                            \
    bf16x8 bfr_[2][2];                                                            \
    _Pragma("unroll") for (int ni = 0; ni < 2; ++ni)                              \
    _Pragma("unroll") for (int kc = 0; kc < 2; ++kc)                              \
        bfr_[ni][kc] = *reinterpret_cast<const bf16x8*>(                          \
            &Bp[SLOT][BP][(((wc * 2 + ni) * 2 + kc) << 9) + l * 8]);              \
    __builtin_amdgcn_s_setprio(1);                                                \
    _Pragma("unroll") for (int mi = 0; mi < 4; ++mi)                              \
    _Pragma("unroll") for (int kc = 0; kc < 2; ++kc) {                            \
        bf16x8 af_ = *reinterpret_cast<const bf16x8*>(                            \
            &Ab[KH][0][(((wr * 4 + mi) * 2 + kc) << 9) + l * 8]);                 \
        _Pragma("unroll") for (int ni = 0; ni < 2; ++ni)                          \
            acc[mi][ni] = __builtin_amdgcn_mfma_f32_16x16x32_bf16(                \
                af_, bfr_[ni][kc], acc[mi][ni], 0, 0, 0);                         \
    }                                                                             \
    if ((BP) <= 1) {                                                              \
        _Pragma("unroll") for (int mi = 0; mi < 4; ++mi)                          \
        _Pragma("unroll") for (int kc = 0; kc < 2; ++kc) {                        \
            bf16x8 af_ = *reinterpret_cast<const bf16x8*>(                        \
                &Ab[KH][1][(((wr * 4 + mi) * 2 + kc) << 9) + l * 8]);             \
            _Pragma("unroll") for (int ni = 0; ni < 2; ++ni)                      \
                acc[mi][ni] = __builtin_amdgcn_mfma_f32_16x16x32_bf16(            \
                    af_, bfr_[ni][kc], acc[mi][ni], 0, 0, 0);                     \
        }                                                                         \
    }                                                                             \
    if ((BP) == 0) {                                                              \
        _Pragma("unroll") for (int mi = 0; mi < 4; ++mi)                          \
        _Pragma("unroll") for (int kc = 0; kc < 2; ++kc)                          \
        _Pragma("unroll") for (int ni = 0; ni < 2; ++ni)                          \
            acc[mi][ni] = __builtin_amdgcn_mfma_f32_16x16x32_bf16(                \
                Al[KH][mi][kc], bfr_[ni][kc], acc[mi][ni], 0, 0, 0);              \
    }                                                                             \
    __builtin_amdgcn_s_setprio(0);                                                \
} while (0)

    STAGE3(0, 0, 0);
    WAITVM(0);
    BAR;

    const double INITD = __hiloint2double(0x7f7fffff, 0);
    double bv[16];
    #pragma unroll
    for (int q = 0; q < 16; ++q) bv[q] = INITD;

    f32x4 acc[4][2];
    float pm[32], yv[2];

    #pragma unroll 1
    for (int nt = 0; nt < 16; ++nt) {
        const int ntn = (nt < 15) ? nt + 1 : 15;

        // ---- Phase A: compute kh0 (slot0); stage kh1 -> slot1 ----
        WAITVM(4);                      // retire prev-B's stage (leave its 4 ZSTs)
        BAR;
        #pragma unroll
        for (int mi = 0; mi < 4; ++mi)
            #pragma unroll
            for (int ni = 0; ni < 2; ++ni) acc[mi][ni] = (f32x4){0.f, 0.f, 0.f, 0.f};
        MLOAD16(nt, 0);
        yv[0] = y2b[nt * 128];
        yv[1] = y2b[nt * 128 + 16];
        FENCE;
        STAGE3(nt, 1, 1);
        FENCE;
        ZST(nt, 0); ZST(nt, 1); ZST(nt, 2); ZST(nt, 3);
        COMPUTE_ONE(0, 0, 0);
        COMPUTE_ONE(1, 0, 0);
        COMPUTE_ONE(2, 0, 0);

        // ---- Phase B: compute kh1 (slot1); stage next kh0 -> slot0 ----
        WAITVM(4);                      // retire A's masks+stage (leave A's 4 ZSTs)
        BAR;
        MLOAD16(nt, 1);
        FENCE;
        STAGE3(ntn, 0, 0);
        FENCE;
        ZST(nt, 4); ZST(nt, 5); ZST(nt, 6); ZST(nt, 7);
        COMPUTE_ONE(0, 1, 1);
        COMPUTE_ONE(1, 1, 1);
        COMPUTE_ONE(2, 1, 1);

        // ---- epilogue: retire B's masks (leave B's stage6+zst4 in flight) ----
        WAITVM(10);
        #pragma unroll
        for (int ni = 0; ni < 2; ++ni) {
            const int c = ch * 2048 + nt * 128 + wc * 32 + ni * 16 + l15;
            #pragma unroll
            for (int mi = 0; mi < 4; ++mi) {
                #pragma unroll
                for (int rg = 0; rg < 4; ++rg) {
                    float d2 = fmaf(acc[mi][ni][rg], -2.0f, x2r[mi * 4 + rg]) + yv[ni];
                    float d  = sqrtf(fmaxf(d2, 0.0f)) * pm[mi * 8 + rg * 2 + ni];
                    double pk = __hiloint2double(__float_as_int(d), c);
                    bv[mi * 4 + rg] = fmin(bv[mi * 4 + rg], pk);
                }
            }
        }
    }
#undef STAGE3
#undef MLOAD16
#undef ZST
#undef COMPUTE_ONE

    WAITVM(0);

    // ---- reduce across 16 col-lanes (packed min), then 4 col-waves via LDS ----
    #pragma unroll
    for (int off = 1; off < 16; off <<= 1) {
        #pragma unroll
        for (int q = 0; q < 16; ++q)
            bv[q] = fmin(bv[q], __shfl_xor(bv[q], off));
    }
    __syncthreads();                    // B LDS free; overlay candidates
    double* cd = reinterpret_cast<double*>(&Bp[0][0][0]);   // [128][4]
    if (l15 == 0) {
        #pragma unroll
        for (int mi = 0; mi < 4; ++mi)
            #pragma unroll
            for (int rg = 0; rg < 4; ++rg) {
                int rowl = wr * 64 + mi * 16 + lg4 * 4 + rg;
                cd[rowl * 4 + wc] = bv[mi * 4 + rg];
            }
    }
    __syncthreads();
    if (tid < 128) {
        double v = fmin(fmin(cd[tid * 4], cd[tid * 4 + 1]),
                        fmin(cd[tid * 4 + 2], cd[tid * 4 + 3]));
        int grow = g0 + tid;
        pv[grow * 2 + ch] = __int_as_float(__double2hiint(v));
        pi[grow * 2 + ch] = __double2loint(v);
    }
}

__global__ __launch_bounds__(256) void k_fin(const float* __restrict__ pv,
                                             const int* __restrict__ pi,
                                             float* __restrict__ out) {
    int t = blockIdx.x * 256 + threadIdx.x;   // row 0..16383
    float v0 = pv[t * 2], v1 = pv[t * 2 + 1];
    int   i0 = pi[t * 2], i1 = pi[t * 2 + 1];
    bool take1 = (v1 < v0) || (v1 == v0 && i1 < i0);
    float v  = take1 ? v1 : v0;
    int   ix = take1 ? i1 : i0;
    out[67108864 + t]         = (float)ix;            // pairs
    out[67108864 + 16384 + t] = v;                    // top_dists
    out[(size_t)t * 4096 + (size_t)ix] = 1.0f;        // one-hot
}

// ================= fallback path (needs only 384 KB ws) =================
__global__ __launch_bounds__(256) void k_rowsq(const float* __restrict__ xd,
                                               const float* __restrict__ yd,
                                               float* __restrict__ ws) {
    int tid  = threadIdx.x;
    int wid  = tid >> 6, lane = tid & 63;
    int gr   = blockIdx.x * 4 + wid;
    const float* src = (gr < 16384) ? (xd + (size_t)gr * 128)
                                    : (yd + (size_t)(gr - 16384) * 128);
    float2 v = reinterpret_cast<const float2*>(src)[lane];
    float s  = v.x * v.x + v.y * v.y;
    for (int off = 32; off > 0; off >>= 1) s += __shfl_down(s, off);
    if (lane == 0) ws[gr] = s;
}

__global__ __launch_bounds__(256, 1) void k_main_fb(const float* __restrict__ xd,
                                                    const float* __restrict__ yd,
                                                    const float* __restrict__ mask,
                                                    const float* __restrict__ ws,
                                                    float* __restrict__ pvals,
                                                    int* __restrict__ pidx,
                                                    float* __restrict__ mm) {
    __shared__ __align__(16) float Xs[128 * 128];
    __shared__ __align__(16) float Ys[128 * 128];
    const int bid  = blockIdx.x;
    const int mh   = bid & 1;
    const int rb   = (bid >> 1) & 31;
    const int b    = bid >> 6;
    const int tid  = threadIdx.x;
    const int ty   = tid >> 4;
    const int tx   = tid & 15;
    const int row0 = rb * 128;
    const int m0   = mh * 2048;
    {
        const float4 z = make_float4(0.f, 0.f, 0.f, 0.f);
        size_t base = ((size_t)(b * 4096 + row0)) * 4096 + (size_t)m0;
        for (int r = 0; r < 128; ++r) {
            float4* p = reinterpret_cast<float4*>(mm + base + (size_t)r * 4096);
            p[tid] = z; p[tid + 256] = z;
        }
    }
    {
        int lrow = tid >> 5, slot = tid & 31;
        for (int p = 0; p < 16; ++p) {
            int row  = p * 8 + lrow;
            float4 v = reinterpret_cast<const float4*>(
                           xd + ((size_t)(b * 4096 + row0 + row)) * 128)[slot];
            int ss = slot ^ (row & 31);
            *reinterpret_cast<float4*>(&Xs[row * 128 + (ss << 2)]) = v;
        }
    }
    float x2r[8];
    #pragma unroll
    for (int i = 0; i < 8; ++i) x2r[i] = ws[b * 4096 + row0 + ty * 8 + i];
    const float* y2g = ws + 16384 + b * 4096;
    float bv[8]; int bi[8];
    #pragma unroll
    for (int i = 0; i < 8; ++i) { bv[i] = 3.4e38f; bi[i] = 0; }
    __syncthreads();
    for (int tile = 0; tile < 16; ++tile) {
        const int mbase = m0 + tile * 128;
        {
            int lrow = tid >> 5, slot = tid & 31;
            for (int p = 0; p < 16; ++p) {
                int row  = p * 8 + lrow;
                float4 v = reinterpret_cast<const float4*>(
                               yd + ((size_t)(b * 4096 + mbase + row)) * 128)[slot];
                int ss = slot ^ (row & 31);
                *reinterpret_cast<float4*>(&Ys[row * 128 + (ss << 2)]) = v;
            }
        }
        __syncthreads();
        float acc[8][8];
        #pragma unroll
        for (int i = 0; i < 8; ++i)
            #pragma unroll
            for (int jj = 0; jj < 8; ++jj) acc[i][jj] = 0.0f;
        #pragma unroll 4
        for (int ks = 0; ks < 32; ++ks) {
            float4 bf[8];
            #pragma unroll
            for (int jj = 0; jj < 8; ++jj) {
                int c = jj * 16 + tx;
                bf[jj] = *reinterpret_cast<const float4*>(&Ys[c * 128 + ((ks ^ (c & 31)) << 2)]);
            }
            #pragma unroll
            for (int i = 0; i < 8; ++i) {
                int r = ty * 8 + i;
                float4 a = *reinterpret_cast<const float4*>(&Xs[r * 128 + ((ks ^ (r & 31)) << 2)]);
                #pragma unroll
                for (int jj = 0; jj < 8; ++jj) {
                    acc[i][jj] = fmaf(a.x, bf[jj].x, acc[i][jj]);
                    acc[i][jj] = fmaf(a.y, bf[jj].y, acc[i][jj]);
                    acc[i][jj] = fmaf(a.z, bf[jj].z, acc[i][jj]);
                    acc[i][jj] = fmaf(a.w, bf[jj].w, acc[i][jj]);
                }
            }
        }
        float y2v[8];
        #pragma unroll
        for (int jj = 0; jj < 8; ++jj) y2v[jj] = y2g[mbase + jj * 16 + tx];
        #pragma unroll
        for (int i = 0; i < 8; ++i) {
            int r = ty * 8 + i;
            const float* mr = mask + ((size_t)(b * 4096 + row0 + r)) * 4096;
            #pragma unroll
            for (int jj = 0; jj < 8; ++jj) {
                int   m  = mbase + jj * 16 + tx;
                float d2 = x2r[i] + y2v[jj] - 2.0f * acc[i][jj];
                float d  = sqrtf(fmaxf(d2, 0.0f)) * mr[m];
                if (d < bv[i]) { bv[i] = d; bi[i] = m; }
            }
        }
        __syncthreads();
    }
    float* candv = Xs;
    int*   candi = reinterpret_cast<int*>(Xs + 2048);
    #pragma unroll
    for (int i = 0; i < 8; ++i) {
        int r = ty * 8 + i;
        candv[r * 16 + tx] = bv[i];
        candi[r * 16 + tx] = bi[i];
    }
    __syncthreads();
    if (tid < 128) {
        int   r  = tid;
        float v  = candv[r * 16];
        int   ix = candi[r * 16];
        for (int t = 1; t < 16; ++t) {
            float v2 = candv[r * 16 + t];
            int   i2 = candi[r * 16 + t];
            if (v2 < v || (v2 == v && i2 < ix)) { v = v2; ix = i2; }
        }
        int grow = b * 4096 + row0 + r;
        pvals[grow * 2 + mh] = v;
        pidx [grow * 2 + mh] = ix;
    }
}

__global__ __launch_bounds__(256) void k_fin_fb(const float* __restrict__ pvals,
                                                const int* __restrict__ pidx,
                                                float* __restrict__ out) {
    int t = blockIdx.x * 256 + threadIdx.x;
    float v0 = pvals[t * 2], v1 = pvals[t * 2 + 1];
    int   i0 = pidx [t * 2], i1 = pidx [t * 2 + 1];
    bool take1 = (v1 < v0) || (v1 == v0 && i1 < i0);
    float v  = take1 ? v1 : v0;
    int   ix = take1 ? i1 : i0;
    out[67108864 + t]         = (float)ix;
    out[67108864 + 16384 + t] = v;
    out[(size_t)t * 4096 + (size_t)ix] = 1.0f;
}

extern "C" void kernel_launch(void* const* d_in, const int* in_sizes, int n_in,
                              void* d_out, int out_size, void* d_ws, size_t ws_size,
                              hipStream_t stream) {
    const float* xd   = (const float*)d_in[0];
    const float* yd   = (const float*)d_in[1];
    const float* mask = (const float*)d_in[2];
    float* out = (float*)d_out;
    float* wsf = (float*)d_ws;

    const size_t need = 131072 + 6 * PS * 2 + 262144;   // 25,559,040
    if (ws_size >= need) {
        unsigned short* pl = (unsigned short*)((char*)d_ws + 131072);
        float* pv = (float*)((char*)d_ws + 131072 + 6 * PS * 2);
        int*   pi = (int*)  ((char*)d_ws + 131072 + 6 * PS * 2 + 131072);
        k_prep <<<2048, 256, 0, stream>>>(xd, yd, pl, wsf);
        k_gemm <<<256,  512, 0, stream>>>(mask, wsf, pl, out, pv, pi);
        k_fin  <<<64,   256, 0, stream>>>(pv, pi, out);
    } else {
        float* pvals = wsf + 32768;
        int*   pidx  = (int*)(wsf + 65536);
        k_rowsq  <<<8192, 256, 0, stream>>>(xd, yd, wsf);
        k_main_fb<<<256,  256, 0, stream>>>(xd, yd, mask, wsf, pvals, pidx, out);
        k_fin_fb <<<64,   256, 0, stream>>>(pvals, pidx, out);
    }
}

// Round 11
// 203.207 us; speedup vs baseline: 4.1237x; 1.1306x over previous
//
#include <hip/hip_runtime.h>

// B=4, N=M=4096, D=128.
// d_out (floats): match_mask [4*4096*4096] | pairs [16384] (as float) | top_dists [16384]
// ws fast path:
//   bytes [0, 131072):        x2 [16384] f32 | y2 [16384] f32
//   bytes [131072, 25296896): planes, 6 x PS elems bf16 (x:h,m,l then y:h,m,l)
//     chunk layout: [b(4)][kh(2)][tile(32)] -> 8192-elem (16 KiB) chunk
//     within chunk: [rb(8)][kc(2)][lane(64)][e(8)], value = in[b][tile*128+rb*16+(l&15)][kh*64+kc*32+(l>>4)*8+e]
//   then pv [16384*2] f32 | pi [16384*2] i32
// Products: hh, hm, mh, mm, hl, lh. Per kh: B=h -> A{h,m,l}; B=m -> A{h,m}; B=l -> A{h}.
// Round-11: no-spill build. Full A (h,m,l x 2kh = 96 KiB) in LDS; B h,m double-slot
// (64 KiB) in LDS; B-l streamed to REGISTERS from L2. 2 phases/nt, counted waits
// NA=NB=8. COMPUTE loops (mi,kc): 3 A ds_reads feed 6 MFMAs.

typedef float  f32x4  __attribute__((ext_vector_type(4)));
typedef short  bf16x8 __attribute__((ext_vector_type(8)));

#define PS ((size_t)2097152)

#define WAITVM_(N) asm volatile("s_waitcnt vmcnt(" #N ")" ::: "memory")
#define WAITVM(N)  WAITVM_(N)
#define BAR        __builtin_amdgcn_s_barrier()
#define FENCE      asm volatile("" ::: "memory")

__device__ __forceinline__ unsigned short f2bf(float x) {
    unsigned u = __float_as_uint(x);
    u += 0x7FFFu + ((u >> 16) & 1u);
    return (unsigned short)(u >> 16);
}
__device__ __forceinline__ float bf2f(unsigned short s) {
    return __uint_as_float(((unsigned)s) << 16);
}
__device__ __forceinline__ void gload_lds16(const void* g, void* l) {
    __builtin_amdgcn_global_load_lds(
        (const __attribute__((address_space(1))) void*)g,
        (__attribute__((address_space(3))) void*)l, 16, 0, 0);
}

// ---- split f32 -> 3 bf16 planes (fragment order) + fused row sum-of-squares ----
__global__ __launch_bounds__(256) void k_prep(const float* __restrict__ xd,
                                              const float* __restrict__ yd,
                                              unsigned short* __restrict__ pl,
                                              float* __restrict__ ws) {
    __shared__ float sm[4][16];
    int bid  = blockIdx.x;            // 0..2047
    int i    = bid >> 10;
    int b    = (bid >> 8) & 3;
    int rblk = bid & 255;
    int tid  = threadIdx.x;
    int kb   = tid >> 6;
    int l    = tid & 63;
    int r    = rblk * 16 + (l & 15);
    int k0   = kb * 32 + ((l >> 4) & 3) * 8;
    const float* src = (i ? yd : xd) + ((size_t)(b * 4096 + r) * 128 + k0);
    float v[8];
    *reinterpret_cast<float4*>(v)     = *reinterpret_cast<const float4*>(src);
    *reinterpret_cast<float4*>(v + 4) = *reinterpret_cast<const float4*>(src + 4);
    bf16x8 hv, mv, lv;
    float s = 0.f;
    #pragma unroll
    for (int e = 0; e < 8; ++e) {
        float x = v[e];
        s = fmaf(x, x, s);
        unsigned short h  = f2bf(x);
        float r1 = x - bf2f(h);
        unsigned short m  = f2bf(r1);
        float r2 = r1 - bf2f(m);
        unsigned short lo = f2bf(r2);
        hv[e] = (short)h; mv[e] = (short)m; lv[e] = (short)lo;
    }
    int rt = rblk >> 3, rb = rblk & 7, kh = kb >> 1, kc = kb & 1;
    size_t base = ((((size_t)((b * 2 + kh) * 32 + rt)) * 8 + rb) * 2 + kc) * 512 + (size_t)l * 8;
    unsigned short* dst = pl + (size_t)(i * 3) * PS;
    *reinterpret_cast<bf16x8*>(dst + base)          = hv;
    *reinterpret_cast<bf16x8*>(dst + base + PS)     = mv;
    *reinterpret_cast<bf16x8*>(dst + base + 2 * PS) = lv;
    s += __shfl_xor(s, 16);
    s += __shfl_xor(s, 32);
    if (l < 16) sm[kb][l] = s;
    __syncthreads();
    if (tid < 16) {
        float t = sm[0][tid] + sm[1][tid] + sm[2][tid] + sm[3][tid];
        ws[(i ? 16384 : 0) + b * 4096 + rblk * 16 + tid] = t;
    }
}

// ---- main: full-A LDS, B h,m LDS + B-l regs, 2-phase/nt counted-wait pipeline ----
__global__ __launch_bounds__(512, 2) void k_gemm(const float* __restrict__ mask,
                                                 const float* __restrict__ ws,
                                                 const unsigned short* __restrict__ pl,
                                                 float* __restrict__ out,
                                                 float* __restrict__ pv,
                                                 int* __restrict__ pi) {
    __shared__ __align__(16) unsigned short Ab[2][3][8192];  // 96 KiB: A h,m,l per kh
    __shared__ __align__(16) unsigned short Bp[2][2][8192];  // 64 KiB: [kh-slot][plane h,m]

    const int bid = blockIdx.x;        // 256 blocks = 1/CU
    const int xcd = bid & 7;
    const int b   = xcd >> 1;          // batch pinned per XCD pair
    const int ch  = xcd & 1;           // col half (2048 cols)
    const int rt  = bid >> 3;          // 128-row tile 0..31
    const int tid = threadIdx.x;
    const int w   = tid >> 6, l = tid & 63;
    const int wr  = w >> 2, wc = w & 3;     // 2x4 waves: 64 rows x 32 cols each
    const int lg4 = (l >> 4) & 3, l15 = l & 15;
    const int g0  = b * 4096 + rt * 128;

    float x2r[16];
    #pragma unroll
    for (int mi = 0; mi < 4; ++mi)
        #pragma unroll
        for (int rg = 0; rg < 4; ++rg)
            x2r[mi * 4 + rg] = ws[g0 + wr * 64 + mi * 16 + lg4 * 4 + rg];

    const float* mrow = mask + (size_t)(g0 + wr * 64 + lg4 * 4) * 4096
                        + ch * 2048 + wc * 32 + l15;
    const float* y2b  = ws + 16384 + b * 4096 + ch * 2048 + wc * 32 + l15;

    // ---- prologue: A (6 chunks) -> LDS; B nt0 kh0 h,m -> slot0; B-l kh0 -> regs ----
    #pragma unroll
    for (int c = 0; c < 6; ++c) {
        const int kh = c >> 1, ap = (c & 1) + ((c >= 4) ? 1 : 0);   // c: (kh,ap) pairs
        // simpler exact mapping below
    }
    #pragma unroll
    for (int kh = 0; kh < 2; ++kh)
        #pragma unroll
        for (int ap = 0; ap < 3; ++ap) {
            const unsigned short* Ac = pl + (size_t)ap * PS
                + (((size_t)((b * 2 + kh) * 32 + rt)) << 13);
            const char* g = (const char*)Ac + w * 1024 + l * 16;
            char* dd = (char*)(&Ab[kh][ap][0]) + w * 1024;
            gload_lds16(g, dd);
            gload_lds16(g + 8192, dd + 8192);
        }

#define STAGE2(NTT, KH, SLOT) do {                                                \
    _Pragma("unroll") for (int bp_ = 0; bp_ < 2; ++bp_) {                         \
        const unsigned short* Bc_ = pl + (size_t)(3 + bp_) * PS                   \
            + (((size_t)((b * 2 + (KH)) * 32 + ch * 16 + (NTT))) << 13);          \
        const char* g_ = (const char*)Bc_ + w * 1024 + l * 16;                    \
        char* d_ = (char*)(&Bp[SLOT][bp_][0]) + w * 1024;                         \
        gload_lds16(g_, d_);                                                      \
        gload_lds16(g_ + 8192, d_ + 8192);                                        \
    }                                                                             \
} while (0)

#define BLLOAD(DST, NTT, KH) do {                                                 \
    const unsigned short* Bc_ = pl + (size_t)5 * PS                               \
        + (((size_t)((b * 2 + (KH)) * 32 + ch * 16 + (NTT))) << 13);              \
    _Pragma("unroll") for (int ni = 0; ni < 2; ++ni)                              \
    _Pragma("unroll") for (int kc = 0; kc < 2; ++kc)                              \
        DST[ni][kc] = *reinterpret_cast<const bf16x8*>(                           \
            Bc_ + (((wc * 2 + ni) * 2 + kc) << 9) + l * 8);                       \
} while (0)

#define MLOAD16(NT, NI) do {                                                      \
    _Pragma("unroll") for (int mi_ = 0; mi_ < 4; ++mi_)                           \
    _Pragma("unroll") for (int rg_ = 0; rg_ < 4; ++rg_)                           \
        pm[mi_ * 8 + rg_ * 2 + (NI)] =                                            \
            mrow[(size_t)(mi_ * 16 + rg_) * 4096 + (NT) * 128 + (NI) * 16];       \
} while (0)

#define ZST(NT, I) do {                                                           \
    const f32x4 z_ = (f32x4){0.f, 0.f, 0.f, 0.f};                                 \
    const int r_ = (tid >> 5) * 8 + (I);                                          \
    *reinterpret_cast<f32x4*>(out + (size_t)(g0 + r_) * 4096                      \
        + ch * 2048 + (NT) * 128 + ((tid & 31) << 2)) = z_;                       \
} while (0)

// per-phase compute: B h,m from LDS slot, B-l from BLREG; A h,m,l from LDS.
// 6 MFMA per (mi,kc,ni): hh, mh, lh, hm, mm, hl.
#define COMPUTE(KH, SLOT, BLREG) do {                                             \
    bf16x8 Bh_[2][2], Bm_[2][2];                                                  \
    _Pragma("unroll") for (int ni = 0; ni < 2; ++ni)                              \
    _Pragma("unroll") for (int kc = 0; kc < 2; ++kc) {                            \
        Bh_[ni][kc] = *reinterpret_cast<const bf16x8*>(                           \
            &Bp[SLOT][0][(((wc * 2 + ni) * 2 + kc) << 9) + l * 8]);               \
        Bm_[ni][kc] = *reinterpret_cast<const bf16x8*>(                           \
            &Bp[SLOT][1][(((wc * 2 + ni) * 2 + kc) << 9) + l * 8]);               \
    }                                                                             \
    __builtin_amdgcn_s_setprio(1);                                                \
    _Pragma("unroll") for (int mi = 0; mi < 4; ++mi)                              \
    _Pragma("unroll") for (int kc = 0; kc < 2; ++kc) {                            \
        const int fo = (((wr * 4 + mi) * 2 + kc) << 9) + l * 8;                   \
        bf16x8 Ah_ = *reinterpret_cast<const bf16x8*>(&Ab[KH][0][fo]);            \
        bf16x8 Am_ = *reinterpret_cast<const bf16x8*>(&Ab[KH][1][fo]);            \
        bf16x8 Al_ = *reinterpret_cast<const bf16x8*>(&Ab[KH][2][fo]);            \
        _Pragma("unroll") for (int ni = 0; ni < 2; ++ni) {                        \
            f32x4 c_ = acc[mi][ni];                                               \
            c_ = __builtin_amdgcn_mfma_f32_16x16x32_bf16(Ah_, Bh_[ni][kc], c_, 0, 0, 0); \
            c_ = __builtin_amdgcn_mfma_f32_16x16x32_bf16(Am_, Bh_[ni][kc], c_, 0, 0, 0); \
            c_ = __builtin_amdgcn_mfma_f32_16x16x32_bf16(Al_, Bh_[ni][kc], c_, 0, 0, 0); \
            c_ = __builtin_amdgcn_mfma_f32_16x16x32_bf16(Ah_, Bm_[ni][kc], c_, 0, 0, 0); \
            c_ = __builtin_amdgcn_mfma_f32_16x16x32_bf16(Am_, Bm_[ni][kc], c_, 0, 0, 0); \
            c_ = __builtin_amdgcn_mfma_f32_16x16x32_bf16(Ah_, BLREG[ni][kc], c_, 0, 0, 0); \
            acc[mi][ni] = c_;                                                     \
        }                                                                         \
    }                                                                             \
    __builtin_amdgcn_s_setprio(0);                                                \
} while (0)

    bf16x8 BlA[2][2], BlB[2][2];
    STAGE2(0, 0, 0);
    BLLOAD(BlA, 0, 0);
    WAITVM(0);
    BAR;

    const double INITD = __hiloint2double(0x7f7fffff, 0);
    double bv[16];
    #pragma unroll
    for (int q = 0; q < 16; ++q) bv[q] = INITD;

    f32x4 acc[4][2];
    float pm[32], yv[2];

    #pragma unroll 1
    for (int nt = 0; nt < 16; ++nt) {
        const int ntn = (nt < 15) ? nt + 1 : 15;

        // ---- Phase A: compute kh0 (slot0 + BlA); stage kh1 -> slot1 + BlB ----
        WAITVM(8);                      // retire slot0's stage (issued prev phase B)
        BAR;
        #pragma unroll
        for (int mi = 0; mi < 4; ++mi)
            #pragma unroll
            for (int ni = 0; ni < 2; ++ni) acc[mi][ni] = (f32x4){0.f, 0.f, 0.f, 0.f};
        MLOAD16(nt, 0);
        yv[0] = y2b[nt * 128];
        yv[1] = y2b[nt * 128 + 16];
        FENCE;
        STAGE2(nt, 1, 1);
        BLLOAD(BlB, nt, 1);
        FENCE;
        ZST(nt, 0); ZST(nt, 1); ZST(nt, 2); ZST(nt, 3);
        COMPUTE(0, 0, BlA);

        // ---- Phase B: compute kh1 (slot1 + BlB); stage next kh0 -> slot0 + BlA ----
        WAITVM(8);                      // retire slot1's stage (masks/yv retired too)
        BAR;
        MLOAD16(nt, 1);
        FENCE;
        STAGE2(ntn, 0, 0);
        BLLOAD(BlA, ntn, 0);
        FENCE;
        ZST(nt, 4); ZST(nt, 5); ZST(nt, 6); ZST(nt, 7);
        COMPUTE(1, 1, BlB);

        // ---- epilogue: pm/yv are VGPR loads (compiler auto-waits) ----
        #pragma unroll
        for (int ni = 0; ni < 2; ++ni) {
            const int c = ch * 2048 + nt * 128 + wc * 32 + ni * 16 + l15;
            #pragma unroll
            for (int mi = 0; mi < 4; ++mi) {
                #pragma unroll
                for (int rg = 0; rg < 4; ++rg) {
                    float d2 = fmaf(acc[mi][ni][rg], -2.0f, x2r[mi * 4 + rg]) + yv[ni];
                    float d  = sqrtf(fmaxf(d2, 0.0f)) * pm[mi * 8 + rg * 2 + ni];
                    double pk = __hiloint2double(__float_as_int(d), c);
                    bv[mi * 4 + rg] = fmin(bv[mi * 4 + rg], pk);
                }
            }
        }
    }
#undef STAGE2
#undef BLLOAD
#undef MLOAD16
#undef ZST
#undef COMPUTE

    WAITVM(0);

    // ---- reduce across 16 col-lanes (packed min), then 4 col-waves via LDS ----
    #pragma unroll
    for (int off = 1; off < 16; off <<= 1) {
        #pragma unroll
        for (int q = 0; q < 16; ++q)
            bv[q] = fmin(bv[q], __shfl_xor(bv[q], off));
    }
    __syncthreads();                    // B LDS free; overlay candidates
    double* cd = reinterpret_cast<double*>(&Bp[0][0][0]);   // [128][4]
    if (l15 == 0) {
        #pragma unroll
        for (int mi = 0; mi < 4; ++mi)
            #pragma unroll
            for (int rg = 0; rg < 4; ++rg) {
                int rowl = wr * 64 + mi * 16 + lg4 * 4 + rg;
                cd[rowl * 4 + wc] = bv[mi * 4 + rg];
            }
    }
    __syncthreads();
    if (tid < 128) {
        double v = fmin(fmin(cd[tid * 4], cd[tid * 4 + 1]),
                        fmin(cd[tid * 4 + 2], cd[tid * 4 + 3]));
        int grow = g0 + tid;
        pv[grow * 2 + ch] = __int_as_float(__double2hiint(v));
        pi[grow * 2 + ch] = __double2loint(v);
    }
}

__global__ __launch_bounds__(256) void k_fin(const float* __restrict__ pv,
                                             const int* __restrict__ pi,
                                             float* __restrict__ out) {
    int t = blockIdx.x * 256 + threadIdx.x;   // row 0..16383
    float v0 = pv[t * 2], v1 = pv[t * 2 + 1];
    int   i0 = pi[t * 2], i1 = pi[t * 2 + 1];
    bool take1 = (v1 < v0) || (v1 == v0 && i1 < i0);
    float v  = take1 ? v1 : v0;
    int   ix = take1 ? i1 : i0;
    out[67108864 + t]         = (float)ix;            // pairs
    out[67108864 + 16384 + t] = v;                    // top_dists
    out[(size_t)t * 4096 + (size_t)ix] = 1.0f;        // one-hot
}

// ================= fallback path (needs only 384 KB ws) =================
__global__ __launch_bounds__(256) void k_rowsq(const float* __restrict__ xd,
                                               const float* __restrict__ yd,
                                               float* __restrict__ ws) {
    int tid  = threadIdx.x;
    int wid  = tid >> 6, lane = tid & 63;
    int gr   = blockIdx.x * 4 + wid;
    const float* src = (gr < 16384) ? (xd + (size_t)gr * 128)
                                    : (yd + (size_t)(gr - 16384) * 128);
    float2 v = reinterpret_cast<const float2*>(src)[lane];
    float s  = v.x * v.x + v.y * v.y;
    for (int off = 32; off > 0; off >>= 1) s += __shfl_down(s, off);
    if (lane == 0) ws[gr] = s;
}

__global__ __launch_bounds__(256, 1) void k_main_fb(const float* __restrict__ xd,
                                                    const float* __restrict__ yd,
                                                    const float* __restrict__ mask,
                                                    const float* __restrict__ ws,
                                                    float* __restrict__ pvals,
                                                    int* __restrict__ pidx,
                                                    float* __restrict__ mm) {
    __shared__ __align__(16) float Xs[128 * 128];
    __shared__ __align__(16) float Ys[128 * 128];
    const int bid  = blockIdx.x;
    const int mh   = bid & 1;
    const int rb   = (bid >> 1) & 31;
    const int b    = bid >> 6;
    const int tid  = threadIdx.x;
    const int ty   = tid >> 4;
    const int tx   = tid & 15;
    const int row0 = rb * 128;
    const int m0   = mh * 2048;
    {
        const float4 z = make_float4(0.f, 0.f, 0.f, 0.f);
        size_t base = ((size_t)(b * 4096 + row0)) * 4096 + (size_t)m0;
        for (int r = 0; r < 128; ++r) {
            float4* p = reinterpret_cast<float4*>(mm + base + (size_t)r * 4096);
            p[tid] = z; p[tid + 256] = z;
        }
    }
    {
        int lrow = tid >> 5, slot = tid & 31;
        for (int p = 0; p < 16; ++p) {
            int row  = p * 8 + lrow;
            float4 v = reinterpret_cast<const float4*>(
                           xd + ((size_t)(b * 4096 + row0 + row)) * 128)[slot];
            int ss = slot ^ (row & 31);
            *reinterpret_cast<float4*>(&Xs[row * 128 + (ss << 2)]) = v;
        }
    }
    float x2r[8];
    #pragma unroll
    for (int i = 0; i < 8; ++i) x2r[i] = ws[b * 4096 + row0 + ty * 8 + i];
    const float* y2g = ws + 16384 + b * 4096;
    float bv[8]; int bi[8];
    #pragma unroll
    for (int i = 0; i < 8; ++i) { bv[i] = 3.4e38f; bi[i] = 0; }
    __syncthreads();
    for (int tile = 0; tile < 16; ++tile) {
        const int mbase = m0 + tile * 128;
        {
            int lrow = tid >> 5, slot = tid & 31;
            for (int p = 0; p < 16; ++p) {
                int row  = p * 8 + lrow;
                float4 v = reinterpret_cast<const float4*>(
                               yd + ((size_t)(b * 4096 + mbase + row)) * 128)[slot];
                int ss = slot ^ (row & 31);
                *reinterpret_cast<float4*>(&Ys[row * 128 + (ss << 2)]) = v;
            }
        }
        __syncthreads();
        float acc[8][8];
        #pragma unroll
        for (int i = 0; i < 8; ++i)
            #pragma unroll
            for (int jj = 0; jj < 8; ++jj) acc[i][jj] = 0.0f;
        #pragma unroll 4
        for (int ks = 0; ks < 32; ++ks) {
            float4 bf[8];
            #pragma unroll
            for (int jj = 0; jj < 8; ++jj) {
                int c = jj * 16 + tx;
                bf[jj] = *reinterpret_cast<const float4*>(&Ys[c * 128 + ((ks ^ (c & 31)) << 2)]);
            }
            #pragma unroll
            for (int i = 0; i < 8; ++i) {
                int r = ty * 8 + i;
                float4 a = *reinterpret_cast<const float4*>(&Xs[r * 128 + ((ks ^ (r & 31)) << 2)]);
                #pragma unroll
                for (int jj = 0; jj < 8; ++jj) {
                    acc[i][jj] = fmaf(a.x, bf[jj].x, acc[i][jj]);
                    acc[i][jj] = fmaf(a.y, bf[jj].y, acc[i][jj]);
                    acc[i][jj] = fmaf(a.z, bf[jj].z, acc[i][jj]);
                    acc[i][jj] = fmaf(a.w, bf[jj].w, acc[i][jj]);
                }
            }
        }
        float y2v[8];
        #pragma unroll
        for (int jj = 0; jj < 8; ++jj) y2v[jj] = y2g[mbase + jj * 16 + tx];
        #pragma unroll
        for (int i = 0; i < 8; ++i) {
            int r = ty * 8 + i;
            const float* mr = mask + ((size_t)(b * 4096 + row0 + r)) * 4096;
            #pragma unroll
            for (int jj = 0; jj < 8; ++jj) {
                int   m  = mbase + jj * 16 + tx;
                float d2 = x2r[i] + y2v[jj] - 2.0f * acc[i][jj];
                float d  = sqrtf(fmaxf(d2, 0.0f)) * mr[m];
                if (d < bv[i]) { bv[i] = d; bi[i] = m; }
            }
        }
        __syncthreads();
    }
    float* candv = Xs;
    int*   candi = reinterpret_cast<int*>(Xs + 2048);
    #pragma unroll
    for (int i = 0; i < 8; ++i) {
        int r = ty * 8 + i;
        candv[r * 16 + tx] = bv[i];
        candi[r * 16 + tx] = bi[i];
    }
    __syncthreads();
    if (tid < 128) {
        int   r  = tid;
        float v  = candv[r * 16];
        int   ix = candi[r * 16];
        for (int t = 1; t < 16; ++t) {
            float v2 = candv[r * 16 + t];
            int   i2 = candi[r * 16 + t];
            if (v2 < v || (v2 == v && i2 < ix)) { v = v2; ix = i2; }
        }
        int grow = b * 4096 + row0 + r;
        pvals[grow * 2 + mh] = v;
        pidx [grow * 2 + mh] = ix;
    }
}

__global__ __launch_bounds__(256) void k_fin_fb(const float* __restrict__ pvals,
                                                const int* __restrict__ pidx,
                                                float* __restrict__ out) {
    int t = blockIdx.x * 256 + threadIdx.x;
    float v0 = pvals[t * 2], v1 = pvals[t * 2 + 1];
    int   i0 = pidx [t * 2], i1 = pidx [t * 2 + 1];
    bool take1 = (v1 < v0) || (v1 == v0 && i1 < i0);
    float v  = take1 ? v1 : v0;
    int   ix = take1 ? i1 : i0;
    out[67108864 + t]         = (float)ix;
    out[67108864 + 16384 + t] = v;
    out[(size_t)t * 4096 + (size_t)ix] = 1.0f;
}

extern "C" void kernel_launch(void* const* d_in, const int* in_sizes, int n_in,
                              void* d_out, int out_size, void* d_ws, size_t ws_size,
                              hipStream_t stream) {
    const float* xd   = (const float*)d_in[0];
    const float* yd   = (const float*)d_in[1];
    const float* mask = (const float*)d_in[2];
    float* out = (float*)d_out;
    float* wsf = (float*)d_ws;

    const size_t need = 131072 + 6 * PS * 2 + 262144;   // 25,559,040
    if (ws_size >= need) {
        unsigned short* pl = (unsigned short*)((char*)d_ws + 131072);
        float* pv = (float*)((char*)d_ws + 131072 + 6 * PS * 2);
        int*   pi = (int*)  ((char*)d_ws + 131072 + 6 * PS * 2 + 131072);
        k_prep <<<2048, 256, 0, stream>>>(xd, yd, pl, wsf);
        k_gemm <<<256,  512, 0, stream>>>(mask, wsf, pl, out, pv, pi);
        k_fin  <<<64,   256, 0, stream>>>(pv, pi, out);
    } else {
        float* pvals = wsf + 32768;
        int*   pidx  = (int*)(wsf + 65536);
        k_rowsq  <<<8192, 256, 0, stream>>>(xd, yd, wsf);
        k_main_fb<<<256,  256, 0, stream>>>(xd, yd, mask, wsf, pvals, pidx, out);
        k_fin_fb <<<64,   256, 0, stream>>>(pvals, pidx, out);
    }
}